// Round 15
// baseline (29.175 us; speedup 1.0000x reference)
//
#include <hip/hip_runtime.h>
#include <math.h>

#define NBLK 4096
#define NT 256
// NBLK * NT * 1 sample/thread = 1048576 = B exactly.
#define BLOB_OFF (NBLK * 8)  // float blob after float2 partials[NBLK]

// blob layout (float offsets; every array starts EVEN so pairs are 8B-aligned)
#define O_I0W1 0
#define O_I0B1 16
#define O_I0W2 24
#define O_I0B2 40
#define O_I1W1 42
#define O_I1B1 66
#define O_I1W2 74
#define O_I1B2 90
#define O_I2W1 92
#define O_I2B1 100
#define O_I2W2 108
#define O_I2B2 124
#define O_G3W1 126
#define O_G3B1 134
#define O_G3W2 142
#define O_G3B2 158
#define O_TBL  160
#define O_G0   208
#define BLOBN  260           // padded to even float2 count (130)

typedef float f32x2 __attribute__((ext_vector_type(2)));

__device__ __forceinline__ f32x2 relu2(f32x2 v) {
    f32x2 z = {0.0f, 0.0f};
    return __builtin_elementwise_max(v, z);
}
__device__ __forceinline__ float zsel(float s, float n) {
    // (sigmoid(s) > n)  <=>  (1-n) > n*exp(-s)
    float e = __expf(-s);
    return (1.0f - n > n * e) ? 1.0f : 0.0f;
}
__device__ __forceinline__ float sp_f(float l) {  // softplus
    return fmaxf(l, 0.0f) + __logf(1.0f + __expf(-fabsf(l)));
}

// -------- kernel A: pack weights into blob + build bilinear coef tables --------
// tbl[(pair*4+t)*2+e]: P0=(sig40,sig41)[z3] P1=(l30,l31)[z4] P2=(SP30,SP31)[z4]
// P3=(l10,l11)[z2] P4=(SP10,SP11)[z2] P5=(muy2[z3], muy1[z1])
__global__ __launch_bounds__(64) void make_blob(
    const float* __restrict__ i0w1, const float* __restrict__ i0b1,
    const float* __restrict__ i0w2, const float* __restrict__ i0b2,
    const float* __restrict__ i1w1, const float* __restrict__ i1b1,
    const float* __restrict__ i1w2, const float* __restrict__ i1b2,
    const float* __restrict__ i2w1, const float* __restrict__ i2b1,
    const float* __restrict__ i2w2, const float* __restrict__ i2b2,
    const float* __restrict__ i3w1, const float* __restrict__ i3b1,
    const float* __restrict__ i3w2, const float* __restrict__ i3b2,
    const float* __restrict__ g1w1, const float* __restrict__ g1b1,
    const float* __restrict__ g1w2, const float* __restrict__ g1b2,
    const float* __restrict__ g2w1, const float* __restrict__ g2b1,
    const float* __restrict__ g2w2, const float* __restrict__ g2b2,
    const float* __restrict__ g3w1, const float* __restrict__ g3b1,
    const float* __restrict__ g3w2, const float* __restrict__ g3b2,
    const float* __restrict__ g4w1, const float* __restrict__ g4b1,
    const float* __restrict__ g4w2, const float* __restrict__ g4b2,
    const float* __restrict__ g5w1, const float* __restrict__ g5b1,
    const float* __restrict__ g5w2, const float* __restrict__ g5b2,
    const float* __restrict__ g0w,
    float* __restrict__ blob)
{
    __shared__ float lds_eval[5][4][2];
    const int tid = threadIdx.x;

    // ---- pack hot weights ----
    if (tid < 16) blob[O_I0W1 + tid] = i0w1[tid];
    if (tid <  8) blob[O_I0B1 + tid] = i0b1[tid];
    if (tid < 16) blob[O_I0W2 + tid] = i0w2[tid];
    if (tid <  2) blob[O_I0B2 + tid] = i0b2[tid];
    if (tid < 24) blob[O_I1W1 + tid] = i1w1[tid];
    if (tid <  8) blob[O_I1B1 + tid] = i1b1[tid];
    if (tid < 16) blob[O_I1W2 + tid] = i1w2[tid];
    if (tid <  2) blob[O_I1B2 + tid] = i1b2[tid];
    if (tid <  8) blob[O_I2W1 + tid] = i2w1[tid];
    if (tid <  8) blob[O_I2B1 + tid] = i2b1[tid];
    if (tid < 16) blob[O_I2W2 + tid] = i2w2[tid];
    if (tid <  2) blob[O_I2B2 + tid] = i2b2[tid];
    if (tid <  8) blob[O_G3W1 + tid] = g3w1[tid];
    if (tid <  8) blob[O_G3B1 + tid] = g3b1[tid];
    if (tid < 16) blob[O_G3W2 + tid] = g3w2[tid];
    if (tid <  2) blob[O_G3B2 + tid] = g3b2[tid];
    if (tid <  2) blob[O_G0   + tid] = g0w[tid];
    if (tid <  2) blob[O_G0 + 2 + tid] = 0.0f;  // pad to BLOBN

    // ---- corner logits of the 5 binary-input MLPs ----
    if (tid < 20) {
        const int m = tid >> 2, c = tid & 3;
        const float z0 = (float)(c & 1), z1f = (float)(c >> 1);
        const float *w1, *bb1, *w2, *bb2; int dout;
        switch (m) {
            case 0:  w1 = i3w1; bb1 = i3b1; w2 = i3w2; bb2 = i3b2; dout = 2; break;
            case 1:  w1 = g1w1; bb1 = g1b1; w2 = g1w2; bb2 = g1b2; dout = 2; break;
            case 2:  w1 = g2w1; bb1 = g2b1; w2 = g2w2; bb2 = g2b2; dout = 1; break;
            case 3:  w1 = g4w1; bb1 = g4b1; w2 = g4w2; bb2 = g4b2; dout = 2; break;
            default: w1 = g5w1; bb1 = g5b1; w2 = g5w2; bb2 = g5b2; dout = 1; break;
        }
        float o0 = bb2[0];
        float o1 = (dout == 2) ? bb2[1] : 0.0f;
        #pragma unroll
        for (int j = 0; j < 8; ++j) {
            float h = fmaxf(bb1[j] + z0 * w1[j] + z1f * w1[8 + j], 0.0f);
            o0 += h * w2[j * dout];
            if (dout == 2) o1 += h * w2[j * 2 + 1];
        }
        lds_eval[m][c][0] = o0;
        lds_eval[m][c][1] = o1;
    }
    __syncthreads();
    // ---- transform corners (id / sigmoid / softplus) -> coefs ----
    if (tid < 12) {
        const int pair = tid >> 1, elem = tid & 1;
        int m, k, tf;
        switch (tid) {
            case 0:  m = 0; k = 0; tf = 1; break;  // sig40
            case 1:  m = 0; k = 1; tf = 1; break;  // sig41
            case 2:  m = 1; k = 0; tf = 0; break;  // l30
            case 3:  m = 1; k = 1; tf = 0; break;  // l31
            case 4:  m = 1; k = 0; tf = 2; break;  // SP30
            case 5:  m = 1; k = 1; tf = 2; break;  // SP31
            case 6:  m = 3; k = 0; tf = 0; break;  // l10
            case 7:  m = 3; k = 1; tf = 0; break;  // l11
            case 8:  m = 3; k = 0; tf = 2; break;  // SP10
            case 9:  m = 3; k = 1; tf = 2; break;  // SP11
            case 10: m = 2; k = 0; tf = 0; break;  // muy2
            default: m = 4; k = 0; tf = 0; break;  // muy1
        }
        float f[4];
        #pragma unroll
        for (int c = 0; c < 4; ++c) {
            float x = lds_eval[m][c][k];
            if (tf == 1)      x = 1.0f / (1.0f + expf(-x));
            else if (tf == 2) x = fmaxf(x, 0.0f) + log1pf(expf(-fabsf(x)));
            f[c] = x;
        }
        blob[O_TBL + (pair * 4 + 0) * 2 + elem] = f[0];
        blob[O_TBL + (pair * 4 + 1) * 2 + elem] = f[1] - f[0];
        blob[O_TBL + (pair * 4 + 2) * 2 + elem] = f[2] - f[0];
        blob[O_TBL + (pair * 4 + 3) * 2 + elem] = f[3] - f[1] - f[2] + f[0];
    }
}

// ------ kernel B: main — weights/coefs staged in LDS via coalesced copy ------
__global__ __launch_bounds__(NT, 8) void wake_main(
    const float* __restrict__ y1, const float* __restrict__ y2,
    const float* __restrict__ n1, const float* __restrict__ n2,
    const float* __restrict__ n3, const float* __restrict__ n4,
    const float* __restrict__ blob,
    float2* __restrict__ partials)
{
    __shared__ __align__(16) float LW[BLOBN];

    const int tid = threadIdx.x;
    const int g = blockIdx.x * NT + tid;

    // per-thread data loads issued BEFORE the LDS copy (overlap VMEM latency)
    const float Y1 = y1[g];
    const float Y2 = y2[g];
    const float2 N1 = reinterpret_cast<const float2*>(n1)[g];
    const float2 N2 = reinterpret_cast<const float2*>(n2)[g];
    const float2 N3 = reinterpret_cast<const float2*>(n3)[g];
    const float2 N4 = reinterpret_cast<const float2*>(n4)[g];

    // coalesced blob -> LDS copy: 130 float2, one barrier, no divergent math
    if (tid < BLOBN / 2) {
        const float2 v = reinterpret_cast<const float2*>(blob)[tid];
        reinterpret_cast<float2*>(LW)[tid] = v;
    }
    __syncthreads();

    // uniform-address LDS pair read (broadcast, conflict-free), k even const
    #define LP(k) (*reinterpret_cast<const f32x2*>(&LW[k]))

    // inf0([y1,y2]) -> z1
    f32x2 acc0 = LP(O_I0B2);
    #pragma unroll
    for (int jp = 0; jp < 4; ++jp) {
        const int j = 2 * jp;
        f32x2 h = relu2(LP(O_I0B1 + j) + Y1 * LP(O_I0W1 + j) + Y2 * LP(O_I0W1 + 8 + j));
        acc0 += h.x * LP(O_I0W2 + 2 * j) + h.y * LP(O_I0W2 + 2 * j + 2);
    }
    const float z10 = zsel(acc0.x, N1.x);
    const float z11 = zsel(acc0.y, N1.y);

    // inf1([y2,z1]) -> z2
    f32x2 acc1 = LP(O_I1B2);
    #pragma unroll
    for (int jp = 0; jp < 4; ++jp) {
        const int j = 2 * jp;
        f32x2 h = relu2(LP(O_I1B1 + j) + Y2 * LP(O_I1W1 + j)
                        + z10 * LP(O_I1W1 + 8 + j) + z11 * LP(O_I1W1 + 16 + j));
        acc1 += h.x * LP(O_I1W2 + 2 * j) + h.y * LP(O_I1W2 + 2 * j + 2);
    }
    const float z20 = zsel(acc1.x, N2.x);
    const float z21 = zsel(acc1.y, N2.y);

    // inf2(y2) -> z3
    f32x2 acc2 = LP(O_I2B2);
    #pragma unroll
    for (int jp = 0; jp < 4; ++jp) {
        const int j = 2 * jp;
        f32x2 h = relu2(LP(O_I2B1 + j) + Y2 * LP(O_I2W1 + j));
        acc2 += h.x * LP(O_I2W2 + 2 * j) + h.y * LP(O_I2W2 + 2 * j + 2);
    }
    const float z30 = zsel(acc2.x, N3.x);
    const float z31 = zsel(acc2.y, N3.y);

    // z4 via tabulated sigmoid over z3 corners
    const float p3 = z30 * z31;
    const f32x2 sg = LP(O_TBL + 0) + z30 * LP(O_TBL + 2) + z31 * LP(O_TBL + 4) + p3 * LP(O_TBL + 6);
    const float z40 = (sg.x > N4.x) ? 1.0f : 0.0f;
    const float z41 = (sg.y > N4.y) ? 1.0f : 0.0f;
    const float p4 = z40 * z41;

    // g3(y2) -> l2 (continuous-input MLP)
    f32x2 l2 = LP(O_G3B2);
    #pragma unroll
    for (int jp = 0; jp < 4; ++jp) {
        const int j = 2 * jp;
        f32x2 h = relu2(LP(O_G3B1 + j) + Y2 * LP(O_G3W1 + j));
        l2 += h.x * LP(O_G3W2 + 2 * j) + h.y * LP(O_G3W2 + 2 * j + 2);
    }

    // table losses, all pairs packed
    const f32x2 l3  = LP(O_TBL + 8)  + z40 * LP(O_TBL + 10) + z41 * LP(O_TBL + 12) + p4 * LP(O_TBL + 14);
    const f32x2 SP3 = LP(O_TBL + 16) + z40 * LP(O_TBL + 18) + z41 * LP(O_TBL + 20) + p4 * LP(O_TBL + 22);
    const float p2 = z20 * z21;
    const f32x2 l1  = LP(O_TBL + 24) + z20 * LP(O_TBL + 26) + z21 * LP(O_TBL + 28) + p2 * LP(O_TBL + 30);
    const f32x2 SP1 = LP(O_TBL + 32) + z20 * LP(O_TBL + 34) + z21 * LP(O_TBL + 36) + p2 * LP(O_TBL + 38);
    const float p1 = z10 * z11;
    const f32x2 zA = {z30, z10}, zB = {z31, z11}, zP = {p3, p1};
    const f32x2 mu = LP(O_TBL + 40) + zA * LP(O_TBL + 42) + zB * LP(O_TBL + 44) + zP * LP(O_TBL + 46);  // (muy2, muy1)
    const f32x2 L4 = LP(O_G0);

    const f32x2 z1v = {z10, z11}, z2v = {z20, z21}, z3v = {z30, z31};
    f32x2 sp2 = {sp_f(l2.x), sp_f(l2.y)};
    f32x2 bsum = (SP1 - l1 * z1v) + (SP3 - l3 * z3v) + (sp2 - l2 * z2v);
    float lz = bsum.x + bsum.y - (L4.x * z40 + L4.y * z41);
    const f32x2 d = {Y2 - mu.x, Y1 - mu.y};
    const f32x2 dd = d * d;
    float ly = dd.x + dd.y;  // *2 applied in the reduce kernel

    // block reduction -> one float2 partial per block (plain store)
    #pragma unroll
    for (int off = 32; off > 0; off >>= 1) {
        lz += __shfl_down(lz, off);
        ly += __shfl_down(ly, off);
    }
    __shared__ float2 wsum[NT / 64];
    const int lane = tid & 63, wid = tid >> 6;
    if (lane == 0) wsum[wid] = make_float2(lz, ly);
    __syncthreads();
    if (tid == 0) {
        float a = 0.0f, b = 0.0f;
        #pragma unroll
        for (int w = 0; w < NT / 64; ++w) { a += wsum[w].x; b += wsum[w].y; }
        partials[blockIdx.x] = make_float2(a, b);
    }
}

// ---------------- kernel C: final reduce ----------------
__global__ __launch_bounds__(256) void wake_reduce(
    const float2* __restrict__ partials, const float* __restrict__ g0w,
    float* __restrict__ out)
{
    const int tid = threadIdx.x;
    float lz = 0.0f, ly = 0.0f;
    #pragma unroll
    for (int i = 0; i < NBLK / 256; ++i) {
        float2 p = partials[tid + i * 256];
        lz += p.x; ly += p.y;
    }
    #pragma unroll
    for (int off = 32; off > 0; off >>= 1) {
        lz += __shfl_down(lz, off);
        ly += __shfl_down(ly, off);
    }
    __shared__ float2 wsum[4];
    const int lane = tid & 63, wid = tid >> 6;
    if (lane == 0) wsum[wid] = make_float2(lz, ly);
    __syncthreads();
    if (tid == 0) {
        float a = 0.0f, b = 0.0f;
        #pragma unroll
        for (int w = 0; w < 4; ++w) { a += wsum[w].x; b += wsum[w].y; }
        const float l40 = g0w[0], l41 = g0w[1];
        const float c4 = fmaxf(l40, 0.0f) + log1pf(expf(-fabsf(l40)))
                       + fmaxf(l41, 0.0f) + log1pf(expf(-fabsf(l41)));
        const float inv = 1.0f / 1048576.0f;
        const float loss_z = a * inv + c4;
        const float loss_y = 2.0f * b * inv + 0.4515827052894548f;
        out[0] = loss_z + loss_y;
        out[1] = loss_z;
        out[2] = loss_y;
    }
}

extern "C" void kernel_launch(void* const* d_in, const int* in_sizes, int n_in,
                              void* d_out, int out_size, void* d_ws, size_t ws_size,
                              hipStream_t stream) {
    const float* p[43];
    for (int i = 0; i < 43; ++i) p[i] = (const float*)d_in[i];
    float2* partials = (float2*)d_ws;
    float* blob = (float*)((char*)d_ws + BLOB_OFF);

    make_blob<<<1, 64, 0, stream>>>(
        p[6], p[7], p[8], p[9],      // inf0
        p[10], p[11], p[12], p[13],  // inf1
        p[14], p[15], p[16], p[17],  // inf2
        p[18], p[19], p[20], p[21],  // inf3
        p[22], p[23], p[24], p[25],  // g1
        p[26], p[27], p[28], p[29],  // g2
        p[30], p[31], p[32], p[33],  // g3
        p[34], p[35], p[36], p[37],  // g4
        p[38], p[39], p[40], p[41],  // g5
        p[42],                       // g0w
        blob);
    wake_main<<<NBLK, NT, 0, stream>>>(
        p[0], p[1], p[2], p[3], p[4], p[5], blob, partials);
    wake_reduce<<<1, 256, 0, stream>>>(partials, p[42], (float*)d_out);
}

// Round 16
// 24.529 us; speedup vs baseline: 1.1894x; 1.1894x over previous
//
#include <hip/hip_runtime.h>
#include <math.h>

#define NBLK 4096
#define NT 256
// NBLK * NT * 1 sample/thread = 1048576 = B exactly.
#define TBL_OFF (NBLK * 8)  // coef table after float2 partials[NBLK]

typedef float f32x2 __attribute__((ext_vector_type(2)));

__device__ __forceinline__ f32x2 relu2(f32x2 v) {
    f32x2 z = {0.0f, 0.0f};
    return __builtin_elementwise_max(v, z);
}
__device__ __forceinline__ float zsel(float s, float n) {
    // (sigmoid(s) > n)  <=>  (1-n) > n*exp(-s)
    float e = __expf(-s);
    return (1.0f - n > n * e) ? 1.0f : 0.0f;
}
__device__ __forceinline__ float sp_f(float l) {  // softplus
    return fmaxf(l, 0.0f) + __logf(1.0f + __expf(-fabsf(l)));
}

// ---------------- kernel A: build bilinear coefficient tables ----------------
// tbl[(pair*4+t)*2+e]: P0=(sig40,sig41)[z3] P1=(l30,l31)[z4] P2=(SP30,SP31)[z4]
// P3=(l10,l11)[z2] P4=(SP10,SP11)[z2] P5=(muy2[z3], muy1[z1])
__global__ __launch_bounds__(64) void make_tables(
    const float* __restrict__ i3w1, const float* __restrict__ i3b1,
    const float* __restrict__ i3w2, const float* __restrict__ i3b2,
    const float* __restrict__ g1w1, const float* __restrict__ g1b1,
    const float* __restrict__ g1w2, const float* __restrict__ g1b2,
    const float* __restrict__ g2w1, const float* __restrict__ g2b1,
    const float* __restrict__ g2w2, const float* __restrict__ g2b2,
    const float* __restrict__ g4w1, const float* __restrict__ g4b1,
    const float* __restrict__ g4w2, const float* __restrict__ g4b2,
    const float* __restrict__ g5w1, const float* __restrict__ g5b1,
    const float* __restrict__ g5w2, const float* __restrict__ g5b2,
    float* __restrict__ tbl)
{
    __shared__ float lds_eval[5][4][2];
    const int tid = threadIdx.x;
    if (tid < 20) {
        const int m = tid >> 2, c = tid & 3;
        const float z0 = (float)(c & 1), z1f = (float)(c >> 1);
        const float *w1, *bb1, *w2, *bb2; int dout;
        switch (m) {
            case 0:  w1 = i3w1; bb1 = i3b1; w2 = i3w2; bb2 = i3b2; dout = 2; break;
            case 1:  w1 = g1w1; bb1 = g1b1; w2 = g1w2; bb2 = g1b2; dout = 2; break;
            case 2:  w1 = g2w1; bb1 = g2b1; w2 = g2w2; bb2 = g2b2; dout = 1; break;
            case 3:  w1 = g4w1; bb1 = g4b1; w2 = g4w2; bb2 = g4b2; dout = 2; break;
            default: w1 = g5w1; bb1 = g5b1; w2 = g5w2; bb2 = g5b2; dout = 1; break;
        }
        float o0 = bb2[0];
        float o1 = (dout == 2) ? bb2[1] : 0.0f;
        #pragma unroll
        for (int j = 0; j < 8; ++j) {
            float h = fmaxf(bb1[j] + z0 * w1[j] + z1f * w1[8 + j], 0.0f);
            o0 += h * w2[j * dout];
            if (dout == 2) o1 += h * w2[j * 2 + 1];
        }
        lds_eval[m][c][0] = o0;
        lds_eval[m][c][1] = o1;
    }
    __syncthreads();
    if (tid < 12) {
        const int pair = tid >> 1, elem = tid & 1;
        int m, k, tf;
        switch (tid) {
            case 0:  m = 0; k = 0; tf = 1; break;  // sig40
            case 1:  m = 0; k = 1; tf = 1; break;  // sig41
            case 2:  m = 1; k = 0; tf = 0; break;  // l30
            case 3:  m = 1; k = 1; tf = 0; break;  // l31
            case 4:  m = 1; k = 0; tf = 2; break;  // SP30
            case 5:  m = 1; k = 1; tf = 2; break;  // SP31
            case 6:  m = 3; k = 0; tf = 0; break;  // l10
            case 7:  m = 3; k = 1; tf = 0; break;  // l11
            case 8:  m = 3; k = 0; tf = 2; break;  // SP10
            case 9:  m = 3; k = 1; tf = 2; break;  // SP11
            case 10: m = 2; k = 0; tf = 0; break;  // muy2
            default: m = 4; k = 0; tf = 0; break;  // muy1
        }
        float f[4];
        #pragma unroll
        for (int c = 0; c < 4; ++c) {
            float x = lds_eval[m][c][k];
            if (tf == 1)      x = 1.0f / (1.0f + expf(-x));
            else if (tf == 2) x = fmaxf(x, 0.0f) + log1pf(expf(-fabsf(x)));
            f[c] = x;
        }
        tbl[(pair * 4 + 0) * 2 + elem] = f[0];
        tbl[(pair * 4 + 1) * 2 + elem] = f[1] - f[0];
        tbl[(pair * 4 + 2) * 2 + elem] = f[2] - f[0];
        tbl[(pair * 4 + 3) * 2 + elem] = f[3] - f[1] - f[2] + f[0];
    }
}

// Weight f32x2 from two ADJACENT SCALAR reads (stays uniform/SGPR — never
// pointer-cast the weight arrays to vector types: R2 bug, demotes to VMEM).
#define WPAIR(ptr, idx) (f32x2{(ptr)[idx], (ptr)[(idx) + 1]})

// ---------------- kernel B: main, 1 sample/thread, 8 waves/SIMD ----------------
__global__ __launch_bounds__(NT, 8) void wake_main(
    const float* __restrict__ y1, const float* __restrict__ y2,
    const float* __restrict__ n1, const float* __restrict__ n2,
    const float* __restrict__ n3, const float* __restrict__ n4,
    const float* __restrict__ i0w1, const float* __restrict__ i0b1,
    const float* __restrict__ i0w2, const float* __restrict__ i0b2,
    const float* __restrict__ i1w1, const float* __restrict__ i1b1,
    const float* __restrict__ i1w2, const float* __restrict__ i1b2,
    const float* __restrict__ i2w1, const float* __restrict__ i2b1,
    const float* __restrict__ i2w2, const float* __restrict__ i2b2,
    const float* __restrict__ g3w1, const float* __restrict__ g3b1,
    const float* __restrict__ g3w2, const float* __restrict__ g3b2,
    const float* __restrict__ g0w,
    const float* __restrict__ tbl,
    float2* __restrict__ partials)
{
    const int tid = threadIdx.x;
    const int g = blockIdx.x * NT + tid;

    // per-thread data: 40 B in 6 coalesced loads, issued up front
    const float Y1 = y1[g];
    const float Y2 = y2[g];
    const float2 N1 = reinterpret_cast<const float2*>(n1)[g];
    const float2 N2 = reinterpret_cast<const float2*>(n2)[g];
    const float2 N3 = reinterpret_cast<const float2*>(n3)[g];
    const float2 N4 = reinterpret_cast<const float2*>(n4)[g];

    // inf0([y1,y2]) -> z1
    f32x2 acc0 = WPAIR(i0b2, 0);
    #pragma unroll
    for (int jp = 0; jp < 4; ++jp) {
        const int j = 2 * jp;
        f32x2 h = relu2(WPAIR(i0b1, j) + Y1 * WPAIR(i0w1, j) + Y2 * WPAIR(i0w1, 8 + j));
        acc0 += h.x * WPAIR(i0w2, 2 * j) + h.y * WPAIR(i0w2, 2 * j + 2);
    }
    const float z10 = zsel(acc0.x, N1.x);
    const float z11 = zsel(acc0.y, N1.y);

    // inf1([y2,z1]) -> z2
    f32x2 acc1 = WPAIR(i1b2, 0);
    #pragma unroll
    for (int jp = 0; jp < 4; ++jp) {
        const int j = 2 * jp;
        f32x2 h = relu2(WPAIR(i1b1, j) + Y2 * WPAIR(i1w1, j)
                        + z10 * WPAIR(i1w1, 8 + j) + z11 * WPAIR(i1w1, 16 + j));
        acc1 += h.x * WPAIR(i1w2, 2 * j) + h.y * WPAIR(i1w2, 2 * j + 2);
    }
    const float z20 = zsel(acc1.x, N2.x);
    const float z21 = zsel(acc1.y, N2.y);

    // inf2(y2) -> z3
    f32x2 acc2 = WPAIR(i2b2, 0);
    #pragma unroll
    for (int jp = 0; jp < 4; ++jp) {
        const int j = 2 * jp;
        f32x2 h = relu2(WPAIR(i2b1, j) + Y2 * WPAIR(i2w1, j));
        acc2 += h.x * WPAIR(i2w2, 2 * j) + h.y * WPAIR(i2w2, 2 * j + 2);
    }
    const float z30 = zsel(acc2.x, N3.x);
    const float z31 = zsel(acc2.y, N3.y);

    // z4 via tabulated sigmoid over z3 corners
    const float p3 = z30 * z31;
    const f32x2 sg = WPAIR(tbl, 0) + z30 * WPAIR(tbl, 2) + z31 * WPAIR(tbl, 4) + p3 * WPAIR(tbl, 6);
    const float z40 = (sg.x > N4.x) ? 1.0f : 0.0f;
    const float z41 = (sg.y > N4.y) ? 1.0f : 0.0f;
    const float p4 = z40 * z41;

    // g3(y2) -> l2 (continuous-input MLP)
    f32x2 l2 = WPAIR(g3b2, 0);
    #pragma unroll
    for (int jp = 0; jp < 4; ++jp) {
        const int j = 2 * jp;
        f32x2 h = relu2(WPAIR(g3b1, j) + Y2 * WPAIR(g3w1, j));
        l2 += h.x * WPAIR(g3w2, 2 * j) + h.y * WPAIR(g3w2, 2 * j + 2);
    }

    // table losses, all pairs packed
    const f32x2 l3  = WPAIR(tbl, 8)  + z40 * WPAIR(tbl, 10) + z41 * WPAIR(tbl, 12) + p4 * WPAIR(tbl, 14);
    const f32x2 SP3 = WPAIR(tbl, 16) + z40 * WPAIR(tbl, 18) + z41 * WPAIR(tbl, 20) + p4 * WPAIR(tbl, 22);
    const float p2 = z20 * z21;
    const f32x2 l1  = WPAIR(tbl, 24) + z20 * WPAIR(tbl, 26) + z21 * WPAIR(tbl, 28) + p2 * WPAIR(tbl, 30);
    const f32x2 SP1 = WPAIR(tbl, 32) + z20 * WPAIR(tbl, 34) + z21 * WPAIR(tbl, 36) + p2 * WPAIR(tbl, 38);
    const float p1 = z10 * z11;
    const f32x2 zA = {z30, z10}, zB = {z31, z11}, zP = {p3, p1};
    const f32x2 mu = WPAIR(tbl, 40) + zA * WPAIR(tbl, 42) + zB * WPAIR(tbl, 44) + zP * WPAIR(tbl, 46);  // (muy2, muy1)
    const float L40 = g0w[0], L41 = g0w[1];

    const f32x2 z1v = {z10, z11}, z2v = {z20, z21}, z3v = {z30, z31};
    f32x2 sp2 = {sp_f(l2.x), sp_f(l2.y)};
    f32x2 bsum = (SP1 - l1 * z1v) + (SP3 - l3 * z3v) + (sp2 - l2 * z2v);
    float lz = bsum.x + bsum.y - (L40 * z40 + L41 * z41);
    const f32x2 d = {Y2 - mu.x, Y1 - mu.y};
    const f32x2 dd = d * d;
    float ly = dd.x + dd.y;  // *2 applied in the reduce kernel

    // block reduction -> one float2 partial per block (plain store)
    #pragma unroll
    for (int off = 32; off > 0; off >>= 1) {
        lz += __shfl_down(lz, off);
        ly += __shfl_down(ly, off);
    }
    __shared__ float2 wsum[NT / 64];
    const int lane = tid & 63, wid = tid >> 6;
    if (lane == 0) wsum[wid] = make_float2(lz, ly);
    __syncthreads();
    if (tid == 0) {
        float a = 0.0f, b = 0.0f;
        #pragma unroll
        for (int w = 0; w < NT / 64; ++w) { a += wsum[w].x; b += wsum[w].y; }
        partials[blockIdx.x] = make_float2(a, b);
    }
}

// ---------------- kernel C: final reduce ----------------
__global__ __launch_bounds__(256) void wake_reduce(
    const float2* __restrict__ partials, const float* __restrict__ g0w,
    float* __restrict__ out)
{
    const int tid = threadIdx.x;
    float lz = 0.0f, ly = 0.0f;
    #pragma unroll
    for (int i = 0; i < NBLK / 256; ++i) {
        float2 p = partials[tid + i * 256];
        lz += p.x; ly += p.y;
    }
    #pragma unroll
    for (int off = 32; off > 0; off >>= 1) {
        lz += __shfl_down(lz, off);
        ly += __shfl_down(ly, off);
    }
    __shared__ float2 wsum[4];
    const int lane = tid & 63, wid = tid >> 6;
    if (lane == 0) wsum[wid] = make_float2(lz, ly);
    __syncthreads();
    if (tid == 0) {
        float a = 0.0f, b = 0.0f;
        #pragma unroll
        for (int w = 0; w < 4; ++w) { a += wsum[w].x; b += wsum[w].y; }
        const float l40 = g0w[0], l41 = g0w[1];
        const float c4 = fmaxf(l40, 0.0f) + log1pf(expf(-fabsf(l40)))
                       + fmaxf(l41, 0.0f) + log1pf(expf(-fabsf(l41)));
        const float inv = 1.0f / 1048576.0f;
        const float loss_z = a * inv + c4;
        const float loss_y = 2.0f * b * inv + 0.4515827052894548f;
        out[0] = loss_z + loss_y;
        out[1] = loss_z;
        out[2] = loss_y;
    }
}

extern "C" void kernel_launch(void* const* d_in, const int* in_sizes, int n_in,
                              void* d_out, int out_size, void* d_ws, size_t ws_size,
                              hipStream_t stream) {
    const float* p[43];
    for (int i = 0; i < 43; ++i) p[i] = (const float*)d_in[i];
    float2* partials = (float2*)d_ws;
    float* tbl = (float*)((char*)d_ws + TBL_OFF);

    // binary-input MLP weights: inf3=18..21, g1=22..25, g2=26..29, g4=34..37, g5=38..41
    make_tables<<<1, 64, 0, stream>>>(
        p[18], p[19], p[20], p[21],
        p[22], p[23], p[24], p[25],
        p[26], p[27], p[28], p[29],
        p[34], p[35], p[36], p[37],
        p[38], p[39], p[40], p[41],
        tbl);
    wake_main<<<NBLK, NT, 0, stream>>>(
        p[0], p[1], p[2], p[3], p[4], p[5],
        p[6], p[7], p[8], p[9],
        p[10], p[11], p[12], p[13],
        p[14], p[15], p[16], p[17],
        p[30], p[31], p[32], p[33],
        p[42], tbl, partials);
    wake_reduce<<<1, 256, 0, stream>>>(partials, p[42], (float*)d_out);
}